// Round 1
// baseline (445.152 us; speedup 1.0000x reference)
//
#include <hip/hip_runtime.h>
#include <math.h>

#define BN_EPS 1e-5f

// pool-block index of pixel p in the 24x24 image: (r/6)*4 + (c/6)
__host__ __device__ constexpr int blk_of(int p) {
    return (p / 144) * 4 + ((p % 24) / 6);
}

// Kernel 1: pooling + encode + 4-qubit circuit + z output + batchnorm partial sums.
// One thread per batch row; 256 rows per block.
__global__ __launch_bounds__(256, 2) void qfc_main_kernel(
    const float* __restrict__ x,
    const float* __restrict__ enc_w,
    const float* __restrict__ enc_b,
    const float* __restrict__ qp,
    float* __restrict__ zout,   // d_out, B x 4 (z before BN)
    float* __restrict__ acc)    // d_ws: [0..3]=sum z, [4..7]=sum z^2
{
    // stride 36 floats: 16B-aligned float4 rows, bank-uniform (8 words/bank = min)
    __shared__ float tile[256 * 36];
    __shared__ float wpack[64];   // [blk*4 + q] = enc_w[q][blk] / 36
    __shared__ float red[32];     // 4 waves x 8 partials

    const int t = threadIdx.x;
    if (t < 64) {
        int j = t >> 2, q = t & 3;
        wpack[t] = enc_w[q * 16 + j] * (1.0f / 36.0f);
    }

    const long long b0 = (long long)blockIdx.x * 256;
    const float* xb = x + b0 * 576;
    const int lrow = t >> 3;          // 0..31
    const int lcol = (t & 7) << 2;    // 0,4,...,28

    // prefetch chunk 0 (32 cols) into registers
    float4 pref[8];
#pragma unroll
    for (int rr = 0; rr < 8; rr++) {
        int row = lrow + rr * 32;
        pref[rr] = *(const float4*)(xb + (long long)row * 576 + lcol);
    }

    float pooled[16];
#pragma unroll
    for (int j = 0; j < 16; j++) pooled[j] = 0.0f;

#pragma unroll
    for (int ck = 0; ck < 18; ck++) {
        // stage current chunk to LDS
#pragma unroll
        for (int rr = 0; rr < 8; rr++) {
            int row = lrow + rr * 32;
            *(float4*)(&tile[row * 36 + lcol]) = pref[rr];
        }
        __syncthreads();
        // issue next chunk's loads (overlap with compute)
        if (ck < 17) {
#pragma unroll
            for (int rr = 0; rr < 8; rr++) {
                int row = lrow + rr * 32;
                pref[rr] = *(const float4*)(xb + (long long)row * 576 + (ck + 1) * 32 + lcol);
            }
        }
        // accumulate this thread's row: constant blk indices after unroll
        const float* trow = &tile[t * 36];
#pragma unroll
        for (int kk = 0; kk < 32; kk += 4) {
            float4 xv = *(const float4*)(&trow[kk]);
            const int p = ck * 32 + kk;
            pooled[blk_of(p + 0)] += xv.x;
            pooled[blk_of(p + 1)] += xv.y;
            pooled[blk_of(p + 2)] += xv.z;
            pooled[blk_of(p + 3)] += xv.w;
        }
        __syncthreads();
    }

    // encode: encoded[q] = sum_j pooled[j]*enc_w[q][j]/36 + enc_b[q]
    float e0 = enc_b[0], e1 = enc_b[1], e2 = enc_b[2], e3 = enc_b[3];
#pragma unroll
    for (int j = 0; j < 16; j++) {
        float4 w = *(const float4*)(&wpack[j * 4]);
        float pj = pooled[j];
        e0 += pj * w.x; e1 += pj * w.y; e2 += pj * w.z; e3 += pj * w.w;
    }
    float enc[4] = {e0, e1, e2, e3};

    // ---- 4-qubit circuit, 16 complex amplitudes in registers ----
    // qubit q <-> index bit (3-q). Initial state |0000>.
    float sr[16], si[16];
#pragma unroll
    for (int i = 0; i < 16; i++) { sr[i] = (i == 0) ? 1.0f : 0.0f; si[i] = 0.0f; }

#pragma unroll
    for (int layer = 0; layer < 2; layer++) {
#pragma unroll
        for (int q = 0; q < 4; q++) {
            float s, c;
            __sincosf(0.5f * enc[q], &s, &c);
            float zs, zc;
            __sincosf(0.5f * qp[layer * 4 + q], &zs, &zc);
            const int m = 8 >> q;  // 1 << (3-q)
#pragma unroll
            for (int i0 = 0; i0 < 16; i0++) {
                if (i0 & m) continue;
                const int i1 = i0 | m;
                float ar = sr[i0], ai = si[i0], br = sr[i1], bi = si[i1];
                // RY(enc[q])
                float n0r = c * ar - s * br, n0i = c * ai - s * bi;
                float n1r = s * ar + c * br, n1i = s * ai + c * bi;
                // RZ(qp): amp0 *= (zc - i*zs), amp1 *= (zc + i*zs)
                sr[i0] = zc * n0r + zs * n0i;  si[i0] = zc * n0i - zs * n0r;
                sr[i1] = zc * n1r - zs * n1i;  si[i1] = zc * n1i + zs * n1r;
            }
        }
        // CNOT ring: (0,1),(1,2),(2,3),(3,0): if control bit set, flip target bit
#pragma unroll
        for (int g = 0; g < 4; g++) {
            const int cmask = 8 >> g;
            const int tmask = 8 >> ((g + 1) & 3);
#pragma unroll
            for (int i = 0; i < 16; i++) {
                if ((i & cmask) && !(i & tmask)) {
                    const int j = i | tmask;
                    float tr = sr[i]; sr[i] = sr[j]; sr[j] = tr;
                    float ti = si[i]; si[i] = si[j]; si[j] = ti;
                }
            }
        }
    }

    // z[q] = sum_i |amp_i|^2 * (1 - 2*bit(i,q))
    float z0 = 0, z1 = 0, z2 = 0, z3 = 0;
#pragma unroll
    for (int i = 0; i < 16; i++) {
        float p = sr[i] * sr[i] + si[i] * si[i];
        z0 += (i & 8) ? -p : p;
        z1 += (i & 4) ? -p : p;
        z2 += (i & 2) ? -p : p;
        z3 += (i & 1) ? -p : p;
    }

    // write z (pre-BN) to d_out, coalesced float4
    float4 zv; zv.x = z0; zv.y = z1; zv.z = z2; zv.w = z3;
    *(float4*)(&zout[(b0 + t) * 4]) = zv;

    // batchnorm partial sums: wave shuffle reduce 8 values, then LDS, then atomics
    float v[8] = {z0, z1, z2, z3, z0 * z0, z1 * z1, z2 * z2, z3 * z3};
#pragma unroll
    for (int i = 0; i < 8; i++) {
        float s = v[i];
#pragma unroll
        for (int off = 32; off > 0; off >>= 1)
            s += __shfl_xor(s, off, 64);
        v[i] = s;
    }
    const int wave = t >> 6, lane = t & 63;
    if (lane == 0) {
#pragma unroll
        for (int i = 0; i < 8; i++) red[wave * 8 + i] = v[i];
    }
    __syncthreads();
    if (t < 8) {
        float s = red[t] + red[8 + t] + red[16 + t] + red[24 + t];
        atomicAdd(&acc[t], s);
    }
}

// Kernel 2: in-place batchnorm on d_out. One thread = one row (float4).
__global__ __launch_bounds__(256) void qfc_bn_kernel(
    float* __restrict__ out, const float* __restrict__ acc,
    const float* __restrict__ bn_w, const float* __restrict__ bn_b, int B)
{
    const int b = blockIdx.x * 256 + threadIdx.x;
    if (b >= B) return;
    const float invB = 1.0f / (float)B;
    float m0 = acc[0] * invB, m1 = acc[1] * invB, m2 = acc[2] * invB, m3 = acc[3] * invB;
    float s0 = rsqrtf(fmaxf(acc[4] * invB - m0 * m0, 0.0f) + BN_EPS);
    float s1 = rsqrtf(fmaxf(acc[5] * invB - m1 * m1, 0.0f) + BN_EPS);
    float s2 = rsqrtf(fmaxf(acc[6] * invB - m2 * m2, 0.0f) + BN_EPS);
    float s3 = rsqrtf(fmaxf(acc[7] * invB - m3 * m3, 0.0f) + BN_EPS);
    float4 z = ((float4*)out)[b];
    z.x = (z.x - m0) * s0 * bn_w[0] + bn_b[0];
    z.y = (z.y - m1) * s1 * bn_w[1] + bn_b[1];
    z.z = (z.z - m2) * s2 * bn_w[2] + bn_b[2];
    z.w = (z.w - m3) * s3 * bn_w[3] + bn_b[3];
    ((float4*)out)[b] = z;
}

extern "C" void kernel_launch(void* const* d_in, const int* in_sizes, int n_in,
                              void* d_out, int out_size, void* d_ws, size_t ws_size,
                              hipStream_t stream) {
    const float* x     = (const float*)d_in[0];
    const float* enc_w = (const float*)d_in[1];
    const float* enc_b = (const float*)d_in[2];
    const float* qp    = (const float*)d_in[3];
    const float* bn_w  = (const float*)d_in[4];
    const float* bn_b  = (const float*)d_in[5];
    float* out = (float*)d_out;
    float* acc = (float*)d_ws;

    const int B = in_sizes[0] / 576;  // 131072

    // zero the 8 batchnorm accumulators (d_ws is re-poisoned before every launch)
    hipMemsetAsync(acc, 0, 8 * sizeof(float), stream);

    qfc_main_kernel<<<B / 256, 256, 0, stream>>>(x, enc_w, enc_b, qp, out, acc);
    qfc_bn_kernel<<<(B + 255) / 256, 256, 0, stream>>>(out, acc, bn_w, bn_b, B);
}

// Round 2
// 413.294 us; speedup vs baseline: 1.0771x; 1.0771x over previous
//
#include <hip/hip_runtime.h>
#include <math.h>

#define BN_EPS 1e-5f

// Kernel 1: pooling + encode + 4-qubit circuit + z output + batchnorm partials.
// 8 threads per image, each owning a contiguous 72-float strip (= image rows
// 3j..3j+2, all in pool-row-block rb = j>>1). Pool-col-block of element q is
// (q%24)/6 — compile-time after unroll. No LDS staging, no hot-path barriers.
__global__ __launch_bounds__(256, 4) void qfc_main_kernel(
    const float* __restrict__ x,
    const float* __restrict__ enc_w,
    const float* __restrict__ enc_b,
    const float* __restrict__ qp,
    float* __restrict__ zout,   // d_out, B x 4 (z before BN)
    float* __restrict__ acc)    // d_ws: 8 groups x (4 sum, 4 sumsq)
{
    __shared__ float wpack[64];   // [blk*4 + q] = enc_w[q][blk] / 36
    __shared__ float red[32];     // 4 waves x 8 partials

    const int t = threadIdx.x;
    if (t < 64) {
        int blk = t >> 2, q = t & 3;
        wpack[t] = enc_w[q * 16 + blk] * (1.0f / 36.0f);
    }
    __syncthreads();

    const int j = t & 7;                               // strip within image
    const long long img = (long long)blockIdx.x * 32 + (t >> 3);
    const float* base = x + img * 576 + j * 72;

    // 18 independent float4 loads covering this thread's 288B strip
    float4 v[18];
#pragma unroll
    for (int k = 0; k < 18; k++) v[k] = *(const float4*)(base + k * 4);

    // accumulate into 4 col-block registers (index compile-time)
    float colacc[4] = {0.f, 0.f, 0.f, 0.f};
#pragma unroll
    for (int k = 0; k < 18; k++) {
        const float e[4] = {v[k].x, v[k].y, v[k].z, v[k].w};
#pragma unroll
        for (int ee = 0; ee < 4; ee++) {
            const int q = k * 4 + ee;          // 0..71, compile-time
            const int cb = (q % 24) / 6;       // compile-time
            colacc[cb] += e[ee];
        }
    }

    // per-thread encode partials: blk = rb*4+cb, rb = j>>1 (lane-uniform)
    const int rb = j >> 1;
    float4 pe = {0.f, 0.f, 0.f, 0.f};
#pragma unroll
    for (int cb = 0; cb < 4; cb++) {
        float4 w4 = *(const float4*)(&wpack[(rb * 4 + cb) * 4]);
        pe.x += colacc[cb] * w4.x;
        pe.y += colacc[cb] * w4.y;
        pe.z += colacc[cb] * w4.z;
        pe.w += colacc[cb] * w4.w;
    }
    // reduce across the 8 strips of this image (lanes sharing l>>3)
#pragma unroll
    for (int m = 1; m <= 4; m <<= 1) {
        pe.x += __shfl_xor(pe.x, m, 64);
        pe.y += __shfl_xor(pe.y, m, 64);
        pe.z += __shfl_xor(pe.z, m, 64);
        pe.w += __shfl_xor(pe.w, m, 64);
    }
    float enc[4] = {pe.x + enc_b[0], pe.y + enc_b[1], pe.z + enc_b[2], pe.w + enc_b[3]};

    // ---- 4-qubit circuit, 16 complex amplitudes in registers ----
    float sr[16], si[16];
#pragma unroll
    for (int i = 0; i < 16; i++) { sr[i] = (i == 0) ? 1.0f : 0.0f; si[i] = 0.0f; }

#pragma unroll
    for (int layer = 0; layer < 2; layer++) {
#pragma unroll
        for (int q = 0; q < 4; q++) {
            float s, c;
            __sincosf(0.5f * enc[q], &s, &c);
            float zs, zc;
            __sincosf(0.5f * qp[layer * 4 + q], &zs, &zc);
            const int m = 8 >> q;
#pragma unroll
            for (int i0 = 0; i0 < 16; i0++) {
                if (i0 & m) continue;
                const int i1 = i0 | m;
                float ar = sr[i0], ai = si[i0], br = sr[i1], bi = si[i1];
                float n0r = c * ar - s * br, n0i = c * ai - s * bi;
                float n1r = s * ar + c * br, n1i = s * ai + c * bi;
                sr[i0] = zc * n0r + zs * n0i;  si[i0] = zc * n0i - zs * n0r;
                sr[i1] = zc * n1r - zs * n1i;  si[i1] = zc * n1i + zs * n1r;
            }
        }
#pragma unroll
        for (int g = 0; g < 4; g++) {
            const int cmask = 8 >> g;
            const int tmask = 8 >> ((g + 1) & 3);
#pragma unroll
            for (int i = 0; i < 16; i++) {
                if ((i & cmask) && !(i & tmask)) {
                    const int jj = i | tmask;
                    float tr = sr[i]; sr[i] = sr[jj]; sr[jj] = tr;
                    float ti = si[i]; si[i] = si[jj]; si[jj] = ti;
                }
            }
        }
    }

    float z0 = 0, z1 = 0, z2 = 0, z3 = 0;
#pragma unroll
    for (int i = 0; i < 16; i++) {
        float p = sr[i] * sr[i] + si[i] * si[i];
        z0 += (i & 8) ? -p : p;
        z1 += (i & 4) ? -p : p;
        z2 += (i & 2) ? -p : p;
        z3 += (i & 1) ? -p : p;
    }

    // lane j<4 writes component j of this image's z (coalesced 128B per wave)
    const float sel = (j & 2) ? ((j & 1) ? z3 : z2) : ((j & 1) ? z1 : z0);
    if (j < 4) zout[img * 4 + j] = sel;

    // BN partials: lane j holds z[j&3] (j<4) or z[j-4]^2 (j>=4);
    // xor-reduce across the 8 images of the wave (masks 8,16,32)
    float bnv = (j < 4) ? sel : sel * sel;
#pragma unroll
    for (int m = 8; m <= 32; m <<= 1) bnv += __shfl_xor(bnv, m, 64);

    const int lane = t & 63, wv = t >> 6;
    if (lane < 8) red[wv * 8 + lane] = bnv;
    __syncthreads();
    if (t < 8) {
        float s = red[t] + red[8 + t] + red[16 + t] + red[24 + t];
        atomicAdd(&acc[(blockIdx.x & 7) * 8 + t], s);
    }
}

// Kernel 2: in-place batchnorm on d_out. One thread = one row (float4).
__global__ __launch_bounds__(256) void qfc_bn_kernel(
    float* __restrict__ out, const float* __restrict__ acc,
    const float* __restrict__ bn_w, const float* __restrict__ bn_b, int B)
{
    const int b = blockIdx.x * 256 + threadIdx.x;
    if (b >= B) return;
    float sm[8];
#pragma unroll
    for (int i = 0; i < 8; i++) {
        float s = 0.f;
#pragma unroll
        for (int g = 0; g < 8; g++) s += acc[g * 8 + i];
        sm[i] = s;
    }
    const float invB = 1.0f / (float)B;
    float m0 = sm[0] * invB, m1 = sm[1] * invB, m2 = sm[2] * invB, m3 = sm[3] * invB;
    float s0 = rsqrtf(fmaxf(sm[4] * invB - m0 * m0, 0.0f) + BN_EPS);
    float s1 = rsqrtf(fmaxf(sm[5] * invB - m1 * m1, 0.0f) + BN_EPS);
    float s2 = rsqrtf(fmaxf(sm[6] * invB - m2 * m2, 0.0f) + BN_EPS);
    float s3 = rsqrtf(fmaxf(sm[7] * invB - m3 * m3, 0.0f) + BN_EPS);
    float4 z = ((float4*)out)[b];
    z.x = (z.x - m0) * s0 * bn_w[0] + bn_b[0];
    z.y = (z.y - m1) * s1 * bn_w[1] + bn_b[1];
    z.z = (z.z - m2) * s2 * bn_w[2] + bn_b[2];
    z.w = (z.w - m3) * s3 * bn_w[3] + bn_b[3];
    ((float4*)out)[b] = z;
}

extern "C" void kernel_launch(void* const* d_in, const int* in_sizes, int n_in,
                              void* d_out, int out_size, void* d_ws, size_t ws_size,
                              hipStream_t stream) {
    const float* x     = (const float*)d_in[0];
    const float* enc_w = (const float*)d_in[1];
    const float* enc_b = (const float*)d_in[2];
    const float* qp    = (const float*)d_in[3];
    const float* bn_w  = (const float*)d_in[4];
    const float* bn_b  = (const float*)d_in[5];
    float* out = (float*)d_out;
    float* acc = (float*)d_ws;

    const int B = in_sizes[0] / 576;  // 131072

    // zero the 64 batchnorm accumulators (d_ws is re-poisoned every launch)
    hipMemsetAsync(acc, 0, 64 * sizeof(float), stream);

    // 8 threads per image, 32 images per 256-thread block
    qfc_main_kernel<<<B / 32, 256, 0, stream>>>(x, enc_w, enc_b, qp, out, acc);
    qfc_bn_kernel<<<(B + 255) / 256, 256, 0, stream>>>(out, acc, bn_w, bn_b, B);
}